// Round 14
// baseline (499.857 us; speedup 1.0000x reference)
//
#include <hip/hip_runtime.h>
#include <hip/hip_bf16.h>

// ProteinGNNTransformer — round 14: attention fixed-cost amortization —
// KSPLIT 4->2 (halve prologue/epilogue/merge tax), 128-kv mega-iteration
// (halve barriers + loop overhead), branchless prefetch, shfl-fac broadcast.
// P buffer [16][128] with 16-slot XOR swizzle (<=2-way, free).
// GEMMs/spmm/LN unchanged from round 13.

#define NPROT 3000
#define NAA   25
#define NPROP 1071
#define NTOT  4096
#define DIM   256
#define NH    8
#define DHD   32
#define FFD   1024
#define NEDGE 131072
#define LNEPS 1e-5f
#define KSPLIT 2
#define KVQ (NTOT/KSPLIT)

typedef unsigned short u16;
typedef unsigned int u32;
typedef __attribute__((ext_vector_type(8))) short short8v;
typedef __attribute__((ext_vector_type(4))) float float4v;
typedef __attribute__((ext_vector_type(2))) unsigned int uint2v;

__device__ __forceinline__ u16 f2bu(float x){
  union { __hip_bfloat16 h; u16 u; } c; c.h = __float2bfloat16(x); return c.u;
}
__device__ __forceinline__ float bu2f(u16 u){
  union { u32 i; float f; } c; c.i = ((u32)u) << 16; return c.f;
}
__device__ __forceinline__ float4v mfma16(short8v a, short8v b, float4v c){
  return __builtin_amdgcn_mfma_f32_16x16x32_bf16(a, b, c, 0, 0, 0);
}
// pack two f32 to two bf16 (truncation) — v_perm idiom
__device__ __forceinline__ u32 packbf(float lo, float hi){
  u32 ul = __builtin_bit_cast(u32, lo);
  u32 uh = __builtin_bit_cast(u32, hi);
  return (ul >> 16) | (uh & 0xFFFF0000u);
}

// ---------------- embedding concat ----------------
__global__ __launch_bounds__(256) void k_embed(const float* __restrict__ pe, const float* __restrict__ ae,
                                               const float* __restrict__ qe,
                                               float* __restrict__ cur, float* __restrict__ tot){
  int i = blockIdx.x*256 + threadIdx.x;
  int row = i >> 8;
  float v;
  if (row < NPROT)           v = pe[i];
  else if (row < NPROT+NAA)  v = ae[i - NPROT*DIM];
  else                       v = qe[i - (NPROT+NAA)*DIM];
  cur[i] = v; tot[i] = v;
}

__global__ __launch_bounds__(256) void k_zero(int* __restrict__ p, int n){
  int i = blockIdx.x*256 + threadIdx.x; if (i < n) p[i] = 0;
}

// ---------------- weight transpose+convert ----------------
__global__ __launch_bounds__(256) void k_wconv(const float* __restrict__ W, u16* __restrict__ Wt,
                                               int K, int N){
  int n = blockIdx.x;
  for (int k = threadIdx.x; k < K; k += 256)
    Wt[(size_t)n*K + k] = f2bu(W[(size_t)k*N + n]);
}

// ---------------- CSR build ----------------
__global__ __launch_bounds__(256) void k_hist(const int* __restrict__ rows, int* __restrict__ cnt){
  int e = blockIdx.x*256 + threadIdx.x; if (e < NEDGE) atomicAdd(&cnt[rows[e]], 1);
}

__global__ __launch_bounds__(64) void k_scan(const int* __restrict__ cnt, int* __restrict__ rowptr,
                                             int* __restrict__ cursor){
  int lane = threadIdx.x;
  int sum = 0;
  for (int i = 0; i < 64; ++i) sum += cnt[lane*64 + i];
  int pref = sum;
  #pragma unroll
  for (int off = 1; off < 64; off <<= 1){
    int u = __shfl_up(pref, off);
    if (lane >= off) pref += u;
  }
  int run = pref - sum;
  for (int i = 0; i < 64; ++i){
    int c = cnt[lane*64 + i];
    rowptr[lane*64 + i] = run;
    cursor[lane*64 + i] = run;
    run += c;
  }
  if (lane == 63) rowptr[NTOT] = run;
}

__global__ __launch_bounds__(256) void k_scatter(const int* __restrict__ rows, const int* __restrict__ cols,
                                                 const float* __restrict__ vals, int* __restrict__ cursor,
                                                 int* __restrict__ ccol, float* __restrict__ cval){
  int e = blockIdx.x*256 + threadIdx.x; if (e >= NEDGE) return;
  int p = atomicAdd(&cursor[rows[e]], 1);
  ccol[p] = cols[e]; cval[p] = vals[e];
}

// ---------------- SpMM: f32 out + bf16 shadow ----------------
__global__ __launch_bounds__(256) void k_spmm(const int* __restrict__ rowptr, const int* __restrict__ ccol,
                                              const float* __restrict__ cval, const float* __restrict__ x,
                                              float* __restrict__ out, u16* __restrict__ outb){
  int r = blockIdx.x, c = threadIdx.x;
  int s = rowptr[r], e = rowptr[r+1];
  float acc = 0.f;
  for (int i = s; i < e; ++i)
    acc += cval[i] * x[((size_t)ccol[i] << 8) + c];
  out[((size_t)r << 8) + c] = acc;
  outb[((size_t)r << 8) + c] = f2bu(acc);
}

// ---------------- MFMA GEMM, 64x64 tile ----------------
template<int RELU, int BIAS, int BF16OUT>
__global__ __launch_bounds__(256) void k_gemm64(const u16* __restrict__ A, const u16* __restrict__ Wt,
                                                const float* __restrict__ bias, void* __restrict__ Cv,
                                                int M, int K, int Nc){
  __shared__ u16 Al[64*64];
  __shared__ u16 Bl[64*64];
  const int tid = threadIdx.x;
  const int w  = tid >> 6, l = tid & 63, lr = l & 15, g = l >> 4;
  const int row0 = blockIdx.y*64, col0 = blockIdx.x*64;
  const int wm = (w >> 1)*32, wn = (w & 1)*32;
  const int sm = tid >> 2;
  const int so = (tid & 3)*2;
  float4v acc[2][2] = {};

  for (int k0 = 0; k0 < K; k0 += 64){
    const u16* As = A  + (size_t)(row0 + sm)*K + k0 + so*8;
    const u16* Bs = Wt + (size_t)(col0 + sm)*K + k0 + so*8;
    #pragma unroll
    for (int j = 0; j < 2; ++j){
      int o = so + j;
      int slot = o ^ (sm & 7);
      *(short8v*)(Al + sm*64 + slot*8) = *(const short8v*)(As + j*8);
      *(short8v*)(Bl + sm*64 + slot*8) = *(const short8v*)(Bs + j*8);
    }
    __syncthreads();
    #pragma unroll
    for (int kk = 0; kk < 2; ++kk){
      short8v af[2], bfr[2];
      #pragma unroll
      for (int i = 0; i < 2; ++i){
        int am = wm + 16*i + lr;
        af[i]  = *(const short8v*)(Al + am*64 + (((4*kk + g) ^ (am & 7))*8));
        int bn = wn + 16*i + lr;
        bfr[i] = *(const short8v*)(Bl + bn*64 + (((4*kk + g) ^ (bn & 7))*8));
      }
      acc[0][0] = mfma16(af[0], bfr[0], acc[0][0]);
      acc[0][1] = mfma16(af[0], bfr[1], acc[0][1]);
      acc[1][0] = mfma16(af[1], bfr[0], acc[1][0]);
      acc[1][1] = mfma16(af[1], bfr[1], acc[1][1]);
    }
    __syncthreads();
  }

  #pragma unroll
  for (int mi = 0; mi < 2; ++mi){
    #pragma unroll
    for (int ni = 0; ni < 2; ++ni){
      int col = col0 + wn + 16*ni + lr;
      float bv = BIAS ? bias[col] : 0.f;
      #pragma unroll
      for (int j = 0; j < 4; ++j){
        int row = row0 + wm + 16*mi + 4*g + j;
        float v = acc[mi][ni][j] + bv;
        if (RELU) v = fmaxf(v, 0.f);
        if (BF16OUT) ((u16*)Cv)[(size_t)row*Nc + col] = f2bu(v);
        else         ((float*)Cv)[(size_t)row*Nc + col] = v;
      }
    }
  }
}

// ---------------- MFMA flash attention, split-K x2, 128-kv mega-iteration ----------------
// grid (NTOT/64, NH, KSPLIT); 4 waves; lane (lr,g): softmax row q=lr.
// P layout: [q=lr][kv 0..127], 16 octets/row, slot = octet ^ lr (<=2-way conflicts).
__global__ __launch_bounds__(256) void k_attn_mfma(const u16* __restrict__ qbf,
                                                   u16* __restrict__ op,
                                                   float* __restrict__ mbuf, float* __restrict__ lbuf){
  __shared__ u16 Vt[2][2][32*64];      // [buf][subtile][dh][kv] swizzled — 16 KB
  __shared__ u16 Pl[4][16*128];        // per-wave P — 16 KB
  const int h   = blockIdx.y;
  const int ks  = blockIdx.z;
  const int qb  = blockIdx.x * 64;
  const int tid = threadIdx.x;
  const int w   = tid >> 6;
  const int l   = tid & 63;
  const int lr  = l & 15;
  const int g   = l >> 4;
  const int sr  = tid >> 2;
  const int sq  = tid & 3;
  const float SC  = 0.17677669529663687f;          // 1/sqrt(32)
  const float SCL = 0.25503837f;                    // SC * log2(e)
  u16* opart = op + (size_t)ks*NTOT*DIM;

  short8v qf = *(const short8v*)(qbf + (size_t)(qb + 16*w + lr)*768 + h*DHD + 8*g);
  short8v ones;
  #pragma unroll
  for (int j = 0; j < 8; ++j) ones[j] = (short)0x3F80;   // bf16 1.0

  float4v oa0 = {0.f,0.f,0.f,0.f}, oa1 = {0.f,0.f,0.f,0.f};
  float4v accl = {0.f,0.f,0.f,0.f};
  float mrun = -1e30f;
  u16* pw = &Pl[w][0];

  // branchless pipeline regs (last-iter prefetch overruns <=96KB inside qbf's 8MB region)
  const u16* vp = qbf + (size_t)(ks*KVQ + sr)*768 + 512 + h*DHD + 8*sq;
  const u16* kp = qbf + (size_t)(ks*KVQ + lr)*768 + 256 + h*DHD + 8*g;
  short8v vrA = *(const short8v*)vp;
  short8v vrB = *(const short8v*)(vp + (size_t)64*768);
  short8v kf[8];
  #pragma unroll
  for (int i = 0; i < 8; ++i) kf[i] = *(const short8v*)(kp + (size_t)16*i*768);

  const int NIT = KVQ/128;     // 16
  for (int t = 0; t < NIT; ++t){
    u16* vt0 = &Vt[t & 1][0][0];
    u16* vt1 = &Vt[t & 1][1][0];
    // ---- stage both V sub-tiles (transposed + swizzled) ----
    #pragma unroll
    for (int j = 0; j < 8; ++j){
      int row  = 8*sq + j;
      int slot = (sr >> 3) ^ j;
      vt0[row*64 + slot*8 + (sr & 7)] = (u16)vrA[j];
      vt1[row*64 + slot*8 + (sr & 7)] = (u16)vrB[j];
    }
    __syncthreads();
    // ---- prefetch V (t+1), branchless ----
    vp += (size_t)128*768;
    vrA = *(const short8v*)vp;
    vrB = *(const short8v*)(vp + (size_t)64*768);

    // ---- S^T = K·Q over 128 kv (8 MFMAs) ----
    float4v s[8];
    #pragma unroll
    for (int i = 0; i < 8; ++i)
      s[i] = mfma16(kf[i], qf, (float4v){0.f,0.f,0.f,0.f});
    // ---- prefetch K (t+1), branchless ----
    kp += (size_t)128*768;
    #pragma unroll
    for (int i = 0; i < 8; ++i) kf[i] = *(const short8v*)(kp + (size_t)16*i*768);

    // ---- per-lane softmax (q = lr) over 32 values ----
    float pm[8];
    #pragma unroll
    for (int i = 0; i < 8; ++i)
      pm[i] = fmaxf(fmaxf(fmaxf(s[i][0],s[i][1]),s[i][2]),s[i][3]);
    float tm = fmaxf(fmaxf(fmaxf(pm[0],pm[1]),fmaxf(pm[2],pm[3])),
                     fmaxf(fmaxf(pm[4],pm[5]),fmaxf(pm[6],pm[7])));
    tm = fmaxf(tm, __shfl_xor(tm, 16));
    tm = fmaxf(tm, __shfl_xor(tm, 32));
    const bool nomax = __all(tm <= mrun);
    float fac = 1.f;
    if (!nomax){
      float mn = fmaxf(mrun, tm);
      fac = exp2f((mrun - mn)*SCL);
      mrun = mn;
    }
    float mns = mrun*SCL;
    #pragma unroll
    for (int i = 0; i < 8; ++i){
      s[i][0] = exp2f(__builtin_fmaf(s[i][0], SCL, -mns));
      s[i][1] = exp2f(__builtin_fmaf(s[i][1], SCL, -mns));
      s[i][2] = exp2f(__builtin_fmaf(s[i][2], SCL, -mns));
      s[i][3] = exp2f(__builtin_fmaf(s[i][3], SCL, -mns));
    }

    // ---- P -> LDS: 8 b64 writes, slot = octet ^ lr (16 octets/row) ----
    {
      int gh = g >> 1, gl = 4*(g & 1);
      #pragma unroll
      for (int i = 0; i < 8; ++i){
        int o = 2*i + gh;                        // octet of kv=16i+4g
        uint2v* d = (uint2v*)(pw + lr*128 + ((o ^ lr)*8) + gl);
        *d = (uint2v){packbf(s[i][0], s[i][1]), packbf(s[i][2], s[i][3])};
      }
    }

    // ---- rescale O by fac (broadcast via shfl) ----
    if (!nomax){
      float fq0 = __shfl(fac, 4*g + 0);
      float fq1 = __shfl(fac, 4*g + 1);
      float fq2 = __shfl(fac, 4*g + 2);
      float fq3 = __shfl(fac, 4*g + 3);
      oa0[0]*=fq0; oa0[1]*=fq1; oa0[2]*=fq2; oa0[3]*=fq3;
      oa1[0]*=fq0; oa1[1]*=fq1; oa1[2]*=fq2; oa1[3]*=fq3;
      accl[0]*=fq0; accl[1]*=fq1; accl[2]*=fq2; accl[3]*=fq3;
    }

    // ---- O += P V; l += P 1  (4 kk-steps of 32 kv) ----
    #pragma unroll
    for (int kk = 0; kk < 4; ++kk){
      int op8 = (4*kk + g) ^ lr;                 // P octet slot
      short8v pa = *(const short8v*)(pw + lr*128 + op8*8);
      const u16* vt = (kk < 2) ? vt0 : vt1;
      int slotv = (4*(kk & 1) + g) ^ (lr & 7);
      short8v v0 = *(const short8v*)(vt + lr*64        + slotv*8);
      short8v v1 = *(const short8v*)(vt + (lr+16)*64   + slotv*8);
      oa0  = mfma16(pa, v0, oa0);
      oa1  = mfma16(pa, v1, oa1);
      accl = mfma16(pa, ones, accl);
    }
  }

  // ---- epilogue: bf16 unnormalized partials + scaled m + l ----
  #pragma unroll
  for (int j = 0; j < 4; ++j){
    size_t row = (size_t)(qb + 16*w + 4*g + j);
    opart[row*DIM + h*DHD + lr]      = f2bu(oa0[j]);
    opart[row*DIM + h*DHD + 16 + lr] = f2bu(oa1[j]);
  }
  if (l < 16){
    size_t mi = (size_t)(ks*NH + h)*NTOT + qb + 16*w + lr;
    mbuf[mi] = mrun*SC;
  }
  if (lr == 0){
    #pragma unroll
    for (int j = 0; j < 4; ++j){
      size_t mi = (size_t)(ks*NH + h)*NTOT + qb + 16*w + 4*g + j;
      lbuf[mi] = accl[j];
    }
  }
}

// ---------------- split-K merge (2-way) ----------------
__global__ __launch_bounds__(256) void k_attn_merge(const u16* __restrict__ op,
                                                    const float* __restrict__ mbuf, const float* __restrict__ lbuf,
                                                    u16* __restrict__ obf){
  int i = blockIdx.x*256 + threadIdx.x;
  int r = i >> 8, c = i & 255, h = c >> 5;
  float m[KSPLIT], wgt[KSPLIT];
  float M = -1e30f;
  #pragma unroll
  for (int k = 0; k < KSPLIT; ++k){
    m[k] = mbuf[(size_t)(k*NH + h)*NTOT + r];
    M = fmaxf(M, m[k]);
  }
  float L = 0.f, acc = 0.f;
  #pragma unroll
  for (int k = 0; k < KSPLIT; ++k){
    wgt[k] = __expf(m[k] - M);
    L   += wgt[k]*lbuf[(size_t)(k*NH + h)*NTOT + r];
    acc += wgt[k]*bu2f(op[(size_t)k*NTOT*DIM + i]);
  }
  obf[i] = f2bu(acc / L);
}

// ---------------- fused residual + LayerNorm (+bf16 shadow) ----------------
template<int DUAL>
__global__ __launch_bounds__(256) void k_add_ln(const float* __restrict__ a, const float* __restrict__ b,
                                                const float* __restrict__ g, const float* __restrict__ be,
                                                float* __restrict__ out, u16* __restrict__ out2){
  __shared__ float red[4];
  int r = blockIdx.x, c = threadIdx.x;
  float v = a[((size_t)r << 8) + c] + b[((size_t)r << 8) + c];
  float s = v;
  #pragma unroll
  for (int off = 32; off; off >>= 1) s += __shfl_down(s, off);
  if ((c & 63) == 0) red[c >> 6] = s;
  __syncthreads();
  float mean = (red[0]+red[1]+red[2]+red[3]) * (1.f/DIM);
  __syncthreads();
  float d = v - mean;
  float s2 = d*d;
  #pragma unroll
  for (int off = 32; off; off >>= 1) s2 += __shfl_down(s2, off);
  if ((c & 63) == 0) red[c >> 6] = s2;
  __syncthreads();
  float var = (red[0]+red[1]+red[2]+red[3]) * (1.f/DIM);
  float rv = d * rsqrtf(var + LNEPS) * g[c] + be[c];
  out[((size_t)r << 8) + c] = rv;
  if (DUAL) out2[((size_t)r << 8) + c] = f2bu(rv);
}

// ---------------- fused LN2 + update ----------------
__global__ __launch_bounds__(256) void k_add_ln_upd(const float* __restrict__ a, const float* __restrict__ b,
                                                    const float* __restrict__ g, const float* __restrict__ be,
                                                    float* __restrict__ cur, float* __restrict__ tot){
  __shared__ float red[4];
  int r = blockIdx.x, c = threadIdx.x;
  size_t idx = ((size_t)r << 8) + c;
  float v = a[idx] + b[idx];
  float s = v;
  #pragma unroll
  for (int off = 32; off; off >>= 1) s += __shfl_down(s, off);
  if ((c & 63) == 0) red[c >> 6] = s;
  __syncthreads();
  float mean = (red[0]+red[1]+red[2]+red[3]) * (1.f/DIM);
  __syncthreads();
  float d = v - mean;
  float s2 = d*d;
  #pragma unroll
  for (int off = 32; off; off >>= 1) s2 += __shfl_down(s2, off);
  if ((c & 63) == 0) red[c >> 6] = s2;
  __syncthreads();
  float var = (red[0]+red[1]+red[2]+red[3]) * (1.f/DIM);
  float rv = d * rsqrtf(var + LNEPS) * g[c] + be[c];
  float cu = cur[idx] + rv;
  cur[idx] = cu;
  tot[idx] += cu;
}

// ---------------- output ----------------
__global__ __launch_bounds__(256) void k_out(const float* __restrict__ tot, float* __restrict__ out){
  int i = blockIdx.x*256 + threadIdx.x;
  float v = tot[i];
  out[i] = v;
  out[NTOT*DIM + i] = v;
}

extern "C" void kernel_launch(void* const* d_in, const int* in_sizes, int n_in,
                              void* d_out, int out_size, void* d_ws, size_t ws_size,
                              hipStream_t stream){
  const int*   adj_row = (const int*)  d_in[0];
  const int*   adj_col = (const int*)  d_in[1];
  const float* adj_val = (const float*)d_in[2];
  const float* pe   = (const float*)d_in[3];
  const float* ae   = (const float*)d_in[4];
  const float* qe   = (const float*)d_in[5];
  const float* Wqkv = (const float*)d_in[6];
  const float* Wo   = (const float*)d_in[7];
  const float* W1   = (const float*)d_in[8];
  const float* b1   = (const float*)d_in[9];
  const float* W2   = (const float*)d_in[10];
  const float* b2   = (const float*)d_in[11];
  const float* g1   = (const float*)d_in[12];
  const float* be1  = (const float*)d_in[13];
  const float* g2   = (const float*)d_in[14];
  const float* be2  = (const float*)d_in[15];
  float* out = (float*)d_out;

  // ---- workspace (~36.7 MB, layout unchanged) ----
  char* w = (char*)d_ws;
  float* cur  = (float*)w; w += (size_t)NTOT*DIM*4;
  float* tot  = (float*)w; w += (size_t)NTOT*DIM*4;
  float* tf   = (float*)w; w += (size_t)NTOT*DIM*4;
  float* pbuf = (float*)w; w += (size_t)NTOT*DIM*4;        // proj/ffn2 out; attn partials (2x bf16 = 4MB)
  float* x1   = (float*)w; w += (size_t)NTOT*DIM*4;
  u16* tbf    = (u16*)w;   w += (size_t)NTOT*DIM*2;        // spmm bf16; attn m/l
  u16* obf    = (u16*)w;   w += (size_t)NTOT*DIM*2;
  u16* x1b    = (u16*)w;   w += (size_t)NTOT*DIM*2;
  u16* hq     = (u16*)w;   w += (size_t)NTOT*FFD*2;        // qbf ∪ h (8MB; qbf uses 6MB)
  u16* wqkvt  = (u16*)w;   w += (size_t)768*256*2;
  u16* wot    = (u16*)w;   w += (size_t)256*256*2;
  u16* w1t    = (u16*)w;   w += (size_t)1024*256*2;
  u16* w2t    = (u16*)w;   w += (size_t)256*1024*2;
  int* rowptr = (int*)w;   w += (size_t)(NTOT+1)*4;
  int* cnt    = (int*)w;   w += (size_t)NTOT*4;
  int* cursor = (int*)w;   w += (size_t)NTOT*4;
  int* ccol   = (int*)w;   w += (size_t)NEDGE*4;
  float* cval = (float*)w; w += (size_t)NEDGE*4;
  u16* qbf  = hq;
  u16* opbf = (u16*)pbuf;                      // 2 bf16 partials = 4 MB (pbuf region)
  float* mbuf = (float*)tbf;                   // [KSPLIT][NH][NTOT] f32
  float* lbuf = mbuf + (size_t)KSPLIT*NH*NTOT;

  k_zero<<<16, 256, 0, stream>>>(cnt, NTOT);
  k_embed<<<NTOT, 256, 0, stream>>>(pe, ae, qe, cur, tot);
  k_hist<<<NEDGE/256, 256, 0, stream>>>(adj_row, cnt);
  k_scan<<<1, 64, 0, stream>>>(cnt, rowptr, cursor);
  k_scatter<<<NEDGE/256, 256, 0, stream>>>(adj_row, adj_col, adj_val, cursor, ccol, cval);
  k_wconv<<<768,  256, 0, stream>>>(Wqkv, wqkvt, 256, 768);
  k_wconv<<<256,  256, 0, stream>>>(Wo,   wot,   256, 256);
  k_wconv<<<1024, 256, 0, stream>>>(W1,   w1t,   256, 1024);
  k_wconv<<<256,  256, 0, stream>>>(W2,   w2t,  1024, 256);

  for (int blk = 0; blk < 3; ++blk){
    k_spmm<<<NTOT, 256, 0, stream>>>(rowptr, ccol, cval, cur, tf, tbf);
    k_gemm64<0,0,1><<<dim3(768/64, NTOT/64), 256, 0, stream>>>(tbf, wqkvt, nullptr, qbf, NTOT, 256, 768);
    k_attn_mfma<<<dim3(NTOT/64, NH, KSPLIT), 256, 0, stream>>>(qbf, opbf, mbuf, lbuf);
    k_attn_merge<<<NTOT*DIM/256, 256, 0, stream>>>(opbf, mbuf, lbuf, obf);
    k_gemm64<0,0,0><<<dim3(256/64, NTOT/64), 256, 0, stream>>>(obf, wot, nullptr, pbuf, NTOT, 256, 256);
    k_add_ln<1><<<NTOT, 256, 0, stream>>>(tf, pbuf, g1, be1, x1, x1b);
    k_gemm64<1,1,1><<<dim3(1024/64, NTOT/64), 256, 0, stream>>>(x1b, w1t, b1, hq, NTOT, 256, 1024);
    k_gemm64<0,1,0><<<dim3(256/64, NTOT/64), 256, 0, stream>>>(hq, w2t, b2, pbuf, NTOT, 1024, 256);
    k_add_ln_upd<<<NTOT, 256, 0, stream>>>(x1, pbuf, g2, be2, cur, tot);
  }
  k_out<<<NTOT, 256, 0, stream>>>(tot, out);
}

// Round 15
// 476.143 us; speedup vs baseline: 1.0498x; 1.0498x over previous
//
#include <hip/hip_runtime.h>
#include <hip/hip_bf16.h>

// ProteinGNNTransformer — round 15: revert attn to r13 structure (its 64-kv,
// 16.9KB-LDS config is the occupancy/op balance point; r14's mega-iter lost
// occupancy 35->25% and regressed). Changes vs r13: KSPLIT 4->2 (halve merge +
// epilogue tax, attn time KSPLIT-insensitive per r10/r11), defer-max THR=8
// (raw 31.37 — skip path now actually triggers; P bounded by 256, bf16-safe),
// fused single wconv dispatch, k_out folded into final add_ln_upd.

#define NPROT 3000
#define NAA   25
#define NPROP 1071
#define NTOT  4096
#define DIM   256
#define NH    8
#define DHD   32
#define FFD   1024
#define NEDGE 131072
#define LNEPS 1e-5f
#define KSPLIT 2
#define KVQ (NTOT/KSPLIT)

typedef unsigned short u16;
typedef unsigned int u32;
typedef __attribute__((ext_vector_type(8))) short short8v;
typedef __attribute__((ext_vector_type(4))) float float4v;
typedef __attribute__((ext_vector_type(2))) unsigned int uint2v;

__device__ __forceinline__ u16 f2bu(float x){
  union { __hip_bfloat16 h; u16 u; } c; c.h = __float2bfloat16(x); return c.u;
}
__device__ __forceinline__ float bu2f(u16 u){
  union { u32 i; float f; } c; c.i = ((u32)u) << 16; return c.f;
}
__device__ __forceinline__ float4v mfma16(short8v a, short8v b, float4v c){
  return __builtin_amdgcn_mfma_f32_16x16x32_bf16(a, b, c, 0, 0, 0);
}
// pack two f32 to two bf16 (truncation) — v_perm idiom
__device__ __forceinline__ u32 packbf(float lo, float hi){
  u32 ul = __builtin_bit_cast(u32, lo);
  u32 uh = __builtin_bit_cast(u32, hi);
  return (ul >> 16) | (uh & 0xFFFF0000u);
}

// ---------------- embedding concat ----------------
__global__ __launch_bounds__(256) void k_embed(const float* __restrict__ pe, const float* __restrict__ ae,
                                               const float* __restrict__ qe,
                                               float* __restrict__ cur, float* __restrict__ tot){
  int i = blockIdx.x*256 + threadIdx.x;
  int row = i >> 8;
  float v;
  if (row < NPROT)           v = pe[i];
  else if (row < NPROT+NAA)  v = ae[i - NPROT*DIM];
  else                       v = qe[i - (NPROT+NAA)*DIM];
  cur[i] = v; tot[i] = v;
}

__global__ __launch_bounds__(256) void k_zero(int* __restrict__ p, int n){
  int i = blockIdx.x*256 + threadIdx.x; if (i < n) p[i] = 0;
}

// ---------------- fused weight transpose+convert (all 4 weights, 1 dispatch) ----------------
__global__ __launch_bounds__(256) void k_wconv_all(const float* __restrict__ Wqkv, const float* __restrict__ Wo,
                                                   const float* __restrict__ W1, const float* __restrict__ W2,
                                                   u16* __restrict__ wqkvt, u16* __restrict__ wot,
                                                   u16* __restrict__ w1t, u16* __restrict__ w2t){
  int b = blockIdx.x;
  const float* W; u16* Wt; int K, N, n;
  if (b < 768)       { W = Wqkv; Wt = wqkvt; K = 256;  N = 768;  n = b; }
  else if (b < 1024) { W = Wo;   Wt = wot;   K = 256;  N = 256;  n = b - 768; }
  else if (b < 2048) { W = W1;   Wt = w1t;   K = 256;  N = 1024; n = b - 1024; }
  else               { W = W2;   Wt = w2t;   K = 1024; N = 256;  n = b - 2048; }
  for (int k = threadIdx.x; k < K; k += 256)
    Wt[(size_t)n*K + k] = f2bu(W[(size_t)k*N + n]);
}

// ---------------- CSR build ----------------
__global__ __launch_bounds__(256) void k_hist(const int* __restrict__ rows, int* __restrict__ cnt){
  int e = blockIdx.x*256 + threadIdx.x; if (e < NEDGE) atomicAdd(&cnt[rows[e]], 1);
}

__global__ __launch_bounds__(64) void k_scan(const int* __restrict__ cnt, int* __restrict__ rowptr,
                                             int* __restrict__ cursor){
  int lane = threadIdx.x;
  int sum = 0;
  for (int i = 0; i < 64; ++i) sum += cnt[lane*64 + i];
  int pref = sum;
  #pragma unroll
  for (int off = 1; off < 64; off <<= 1){
    int u = __shfl_up(pref, off);
    if (lane >= off) pref += u;
  }
  int run = pref - sum;
  for (int i = 0; i < 64; ++i){
    int c = cnt[lane*64 + i];
    rowptr[lane*64 + i] = run;
    cursor[lane*64 + i] = run;
    run += c;
  }
  if (lane == 63) rowptr[NTOT] = run;
}

__global__ __launch_bounds__(256) void k_scatter(const int* __restrict__ rows, const int* __restrict__ cols,
                                                 const float* __restrict__ vals, int* __restrict__ cursor,
                                                 int* __restrict__ ccol, float* __restrict__ cval){
  int e = blockIdx.x*256 + threadIdx.x; if (e >= NEDGE) return;
  int p = atomicAdd(&cursor[rows[e]], 1);
  ccol[p] = cols[e]; cval[p] = vals[e];
}

// ---------------- SpMM: f32 out + bf16 shadow ----------------
__global__ __launch_bounds__(256) void k_spmm(const int* __restrict__ rowptr, const int* __restrict__ ccol,
                                              const float* __restrict__ cval, const float* __restrict__ x,
                                              float* __restrict__ out, u16* __restrict__ outb){
  int r = blockIdx.x, c = threadIdx.x;
  int s = rowptr[r], e = rowptr[r+1];
  float acc = 0.f;
  for (int i = s; i < e; ++i)
    acc += cval[i] * x[((size_t)ccol[i] << 8) + c];
  out[((size_t)r << 8) + c] = acc;
  outb[((size_t)r << 8) + c] = f2bu(acc);
}

// ---------------- MFMA GEMM, 64x64 tile ----------------
template<int RELU, int BIAS, int BF16OUT>
__global__ __launch_bounds__(256) void k_gemm64(const u16* __restrict__ A, const u16* __restrict__ Wt,
                                                const float* __restrict__ bias, void* __restrict__ Cv,
                                                int M, int K, int Nc){
  __shared__ u16 Al[64*64];
  __shared__ u16 Bl[64*64];
  const int tid = threadIdx.x;
  const int w  = tid >> 6, l = tid & 63, lr = l & 15, g = l >> 4;
  const int row0 = blockIdx.y*64, col0 = blockIdx.x*64;
  const int wm = (w >> 1)*32, wn = (w & 1)*32;
  const int sm = tid >> 2;
  const int so = (tid & 3)*2;
  float4v acc[2][2] = {};

  for (int k0 = 0; k0 < K; k0 += 64){
    const u16* As = A  + (size_t)(row0 + sm)*K + k0 + so*8;
    const u16* Bs = Wt + (size_t)(col0 + sm)*K + k0 + so*8;
    #pragma unroll
    for (int j = 0; j < 2; ++j){
      int o = so + j;
      int slot = o ^ (sm & 7);
      *(short8v*)(Al + sm*64 + slot*8) = *(const short8v*)(As + j*8);
      *(short8v*)(Bl + sm*64 + slot*8) = *(const short8v*)(Bs + j*8);
    }
    __syncthreads();
    #pragma unroll
    for (int kk = 0; kk < 2; ++kk){
      short8v af[2], bfr[2];
      #pragma unroll
      for (int i = 0; i < 2; ++i){
        int am = wm + 16*i + lr;
        af[i]  = *(const short8v*)(Al + am*64 + (((4*kk + g) ^ (am & 7))*8));
        int bn = wn + 16*i + lr;
        bfr[i] = *(const short8v*)(Bl + bn*64 + (((4*kk + g) ^ (bn & 7))*8));
      }
      acc[0][0] = mfma16(af[0], bfr[0], acc[0][0]);
      acc[0][1] = mfma16(af[0], bfr[1], acc[0][1]);
      acc[1][0] = mfma16(af[1], bfr[0], acc[1][0]);
      acc[1][1] = mfma16(af[1], bfr[1], acc[1][1]);
    }
    __syncthreads();
  }

  #pragma unroll
  for (int mi = 0; mi < 2; ++mi){
    #pragma unroll
    for (int ni = 0; ni < 2; ++ni){
      int col = col0 + wn + 16*ni + lr;
      float bv = BIAS ? bias[col] : 0.f;
      #pragma unroll
      for (int j = 0; j < 4; ++j){
        int row = row0 + wm + 16*mi + 4*g + j;
        float v = acc[mi][ni][j] + bv;
        if (RELU) v = fmaxf(v, 0.f);
        if (BF16OUT) ((u16*)Cv)[(size_t)row*Nc + col] = f2bu(v);
        else         ((float*)Cv)[(size_t)row*Nc + col] = v;
      }
    }
  }
}

// ---------------- MFMA flash attention, split-K x2 (r13 structure + defer-max THR) ----------------
__global__ __launch_bounds__(256) void k_attn_mfma(const u16* __restrict__ qbf,
                                                   u16* __restrict__ op,
                                                   float* __restrict__ mbuf, float* __restrict__ lbuf){
  __shared__ u16 Vt[2][32*64];
  __shared__ u16 Pl[4][16*64];
  __shared__ float Fl[4][16];
  const int h   = blockIdx.y;
  const int ks  = blockIdx.z;
  const int qb  = blockIdx.x * 64;
  const int tid = threadIdx.x;
  const int w   = tid >> 6;
  const int l   = tid & 63;
  const int lr  = l & 15;
  const int g   = l >> 4;
  const int sr  = tid >> 2;
  const int sq  = tid & 3;
  const float SC  = 0.17677669529663687f;          // 1/sqrt(32)
  const float SCL = 0.25503837f;                    // SC * log2(e)
  const float DEFER = 31.368f;                      // 8 / SCL: P bounded by 2^8
  u16* opart = op + (size_t)ks*NTOT*DIM;

  short8v qf = *(const short8v*)(qbf + (size_t)(qb + 16*w + lr)*768 + h*DHD + 8*g);
  short8v ones;
  #pragma unroll
  for (int j = 0; j < 8; ++j) ones[j] = (short)0x3F80;   // bf16 1.0

  float4v oa0 = {0.f,0.f,0.f,0.f}, oa1 = {0.f,0.f,0.f,0.f};
  float4v accl = {0.f,0.f,0.f,0.f};                 // row-sums (same D-domain as oa)
  float mrun = -1e30f;                              // per-lane (q = lr), raw domain
  u16* pw = &Pl[w][0];

  const u16* vp = qbf + (size_t)(ks*KVQ + sr)*768 + 512 + h*DHD + 8*sq;
  const u16* kp = qbf + (size_t)(ks*KVQ + lr)*768 + 256 + h*DHD + 8*g;
  short8v vreg = *(const short8v*)vp;
  short8v kf0 = *(const short8v*)(kp);
  short8v kf1 = *(const short8v*)(kp + (size_t)16*768);
  short8v kf2 = *(const short8v*)(kp + (size_t)32*768);
  short8v kf3 = *(const short8v*)(kp + (size_t)48*768);

  const int NIT = KVQ/64;
  for (int t = 0; t < NIT; ++t){
    u16* vt = &Vt[t & 1][0];
    #pragma unroll
    for (int j = 0; j < 8; ++j){
      int row  = 8*sq + j;
      int slot = (sr >> 3) ^ j;
      vt[row*64 + slot*8 + (sr & 7)] = (u16)vreg[j];
    }
    __syncthreads();
    vp += (size_t)64*768;
    if (t + 1 < NIT) vreg = *(const short8v*)vp;

    float4v s0 = mfma16(kf0, qf, (float4v){0.f,0.f,0.f,0.f});
    float4v s1 = mfma16(kf1, qf, (float4v){0.f,0.f,0.f,0.f});
    float4v s2 = mfma16(kf2, qf, (float4v){0.f,0.f,0.f,0.f});
    float4v s3 = mfma16(kf3, qf, (float4v){0.f,0.f,0.f,0.f});
    if (t + 1 < NIT){
      const u16* kn = kp + (size_t)(t+1)*64*768;
      kf0 = *(const short8v*)(kn);
      kf1 = *(const short8v*)(kn + (size_t)16*768);
      kf2 = *(const short8v*)(kn + (size_t)32*768);
      kf3 = *(const short8v*)(kn + (size_t)48*768);
    }

    // ---- tile max (max3-friendly chains) ----
    float m0 = fmaxf(fmaxf(fmaxf(s0[0],s0[1]),s0[2]),s0[3]);
    float m1 = fmaxf(fmaxf(fmaxf(s1[0],s1[1]),s1[2]),s1[3]);
    float m2 = fmaxf(fmaxf(fmaxf(s2[0],s2[1]),s2[2]),s2[3]);
    float m3 = fmaxf(fmaxf(fmaxf(s3[0],s3[1]),s3[2]),s3[3]);
    float tm = fmaxf(fmaxf(fmaxf(m0,m1),m2),m3);
    tm = fmaxf(tm, __shfl_xor(tm, 16));
    tm = fmaxf(tm, __shfl_xor(tm, 32));
    // defer-max: skip rescale unless some row's max grew by > DEFER (raw domain)
    const bool nomax = __all(tm <= mrun + DEFER);
    float fac = 1.f;
    if (!nomax){
      float mn = fmaxf(mrun, tm);
      fac = exp2f((mrun - mn)*SCL);
      mrun = mn;
    }
    float mns = mrun*SCL;
    #pragma unroll
    for (int j = 0; j < 4; ++j){
      s0[j] = exp2f(__builtin_fmaf(s0[j], SCL, -mns));
      s1[j] = exp2f(__builtin_fmaf(s1[j], SCL, -mns));
      s2[j] = exp2f(__builtin_fmaf(s2[j], SCL, -mns));
      s3[j] = exp2f(__builtin_fmaf(s3[j], SCL, -mns));
    }

    // ---- P -> LDS: truncation-pack + b64 writes ----
    {
      int gh = g >> 1, gl = 4*(g & 1);
      uint2v* d0 = (uint2v*)(pw + lr*64 + ((0 + gh) ^ (lr & 7))*8 + gl);
      uint2v* d1 = (uint2v*)(pw + lr*64 + ((2 + gh) ^ (lr & 7))*8 + gl);
      uint2v* d2 = (uint2v*)(pw + lr*64 + ((4 + gh) ^ (lr & 7))*8 + gl);
      uint2v* d3 = (uint2v*)(pw + lr*64 + ((6 + gh) ^ (lr & 7))*8 + gl);
      *d0 = (uint2v){packbf(s0[0],s0[1]), packbf(s0[2],s0[3])};
      *d1 = (uint2v){packbf(s1[0],s1[1]), packbf(s1[2],s1[3])};
      *d2 = (uint2v){packbf(s2[0],s2[1]), packbf(s2[2],s2[3])};
      *d3 = (uint2v){packbf(s3[0],s3[1]), packbf(s3[2],s3[3])};
    }

    if (!nomax){
      if (g == 0) Fl[w][lr] = fac;
      float fq0 = Fl[w][4*g+0], fq1 = Fl[w][4*g+1], fq2 = Fl[w][4*g+2], fq3 = Fl[w][4*g+3];
      oa0[0]*=fq0; oa0[1]*=fq1; oa0[2]*=fq2; oa0[3]*=fq3;
      oa1[0]*=fq0; oa1[1]*=fq1; oa1[2]*=fq2; oa1[3]*=fq3;
      accl[0]*=fq0; accl[1]*=fq1; accl[2]*=fq2; accl[3]*=fq3;
    }

    // ---- O += P V; l += P 1 ----
    #pragma unroll
    for (int kk = 0; kk < 2; ++kk){
      int slotp = (4*kk + g) ^ (lr & 7);
      short8v pa = *(const short8v*)(pw + lr*64 + slotp*8);
      short8v v0 = *(const short8v*)(vt + lr*64        + slotp*8);
      short8v v1 = *(const short8v*)(vt + (lr+16)*64   + slotp*8);
      oa0  = mfma16(pa, v0, oa0);
      oa1  = mfma16(pa, v1, oa1);
      accl = mfma16(pa, ones, accl);
    }
  }

  // ---- epilogue: bf16 unnormalized partials + scaled m + l ----
  #pragma unroll
  for (int j = 0; j < 4; ++j){
    size_t row = (size_t)(qb + 16*w + 4*g + j);
    opart[row*DIM + h*DHD + lr]      = f2bu(oa0[j]);
    opart[row*DIM + h*DHD + 16 + lr] = f2bu(oa1[j]);
  }
  if (l < 16){
    size_t mi = (size_t)(ks*NH + h)*NTOT + qb + 16*w + lr;
    mbuf[mi] = mrun*SC;
  }
  if (lr == 0){
    #pragma unroll
    for (int j = 0; j < 4; ++j){
      size_t mi = (size_t)(ks*NH + h)*NTOT + qb + 16*w + 4*g + j;
      lbuf[mi] = accl[j];
    }
  }
}

// ---------------- split-K merge (2-way) ----------------
__global__ __launch_bounds__(256) void k_attn_merge(const u16* __restrict__ op,
                                                    const float* __restrict__ mbuf, const float* __restrict__ lbuf,
                                                    u16* __restrict__ obf){
  int i = blockIdx.x*256 + threadIdx.x;
  int r = i >> 8, c = i & 255, h = c >> 5;
  float m[KSPLIT], wgt[KSPLIT];
  float M = -1e30f;
  #pragma unroll
  for (int k = 0; k < KSPLIT; ++k){
    m[k] = mbuf[(size_t)(k*NH + h)*NTOT + r];
    M = fmaxf(M, m[k]);
  }
  float L = 0.f, acc = 0.f;
  #pragma unroll
  for (int k = 0; k < KSPLIT; ++k){
    wgt[k] = __expf(m[k] - M);
    L   += wgt[k]*lbuf[(size_t)(k*NH + h)*NTOT + r];
    acc += wgt[k]*bu2f(op[(size_t)k*NTOT*DIM + i]);
  }
  obf[i] = f2bu(acc / L);
}

// ---------------- fused residual + LayerNorm (+bf16 shadow) ----------------
template<int DUAL>
__global__ __launch_bounds__(256) void k_add_ln(const float* __restrict__ a, const float* __restrict__ b,
                                                const float* __restrict__ g, const float* __restrict__ be,
                                                float* __restrict__ out, u16* __restrict__ out2){
  __shared__ float red[4];
  int r = blockIdx.x, c = threadIdx.x;
  float v = a[((size_t)r << 8) + c] + b[((size_t)r << 8) + c];
  float s = v;
  #pragma unroll
  for (int off = 32; off; off >>= 1) s += __shfl_down(s, off);
  if ((c & 63) == 0) red[c >> 6] = s;
  __syncthreads();
  float mean = (red[0]+red[1]+red[2]+red[3]) * (1.f/DIM);
  __syncthreads();
  float d = v - mean;
  float s2 = d*d;
  #pragma unroll
  for (int off = 32; off; off >>= 1) s2 += __shfl_down(s2, off);
  if ((c & 63) == 0) red[c >> 6] = s2;
  __syncthreads();
  float var = (red[0]+red[1]+red[2]+red[3]) * (1.f/DIM);
  float rv = d * rsqrtf(var + LNEPS) * g[c] + be[c];
  out[((size_t)r << 8) + c] = rv;
  if (DUAL) out2[((size_t)r << 8) + c] = f2bu(rv);
}

// ---------------- fused LN2 + update (+final output copy) ----------------
template<int FINAL>
__global__ __launch_bounds__(256) void k_add_ln_upd(const float* __restrict__ a, const float* __restrict__ b,
                                                    const float* __restrict__ g, const float* __restrict__ be,
                                                    float* __restrict__ cur, float* __restrict__ tot,
                                                    float* __restrict__ out){
  __shared__ float red[4];
  int r = blockIdx.x, c = threadIdx.x;
  size_t idx = ((size_t)r << 8) + c;
  float v = a[idx] + b[idx];
  float s = v;
  #pragma unroll
  for (int off = 32; off; off >>= 1) s += __shfl_down(s, off);
  if ((c & 63) == 0) red[c >> 6] = s;
  __syncthreads();
  float mean = (red[0]+red[1]+red[2]+red[3]) * (1.f/DIM);
  __syncthreads();
  float d = v - mean;
  float s2 = d*d;
  #pragma unroll
  for (int off = 32; off; off >>= 1) s2 += __shfl_down(s2, off);
  if ((c & 63) == 0) red[c >> 6] = s2;
  __syncthreads();
  float var = (red[0]+red[1]+red[2]+red[3]) * (1.f/DIM);
  float rv = d * rsqrtf(var + LNEPS) * g[c] + be[c];
  float cu = cur[idx] + rv;
  cur[idx] = cu;
  float tv = tot[idx] + cu;
  tot[idx] = tv;
  if (FINAL){
    out[idx] = tv;
    out[(size_t)NTOT*DIM + idx] = tv;
  }
}

extern "C" void kernel_launch(void* const* d_in, const int* in_sizes, int n_in,
                              void* d_out, int out_size, void* d_ws, size_t ws_size,
                              hipStream_t stream){
  const int*   adj_row = (const int*)  d_in[0];
  const int*   adj_col = (const int*)  d_in[1];
  const float* adj_val = (const float*)d_in[2];
  const float* pe   = (const float*)d_in[3];
  const float* ae   = (const float*)d_in[4];
  const float* qe   = (const float*)d_in[5];
  const float* Wqkv = (const float*)d_in[6];
  const float* Wo   = (const float*)d_in[7];
  const float* W1   = (const float*)d_in[8];
  const float* b1   = (const float*)d_in[9];
  const float* W2   = (const float*)d_in[10];
  const float* b2   = (const float*)d_in[11];
  const float* g1   = (const float*)d_in[12];
  const float* be1  = (const float*)d_in[13];
  const float* g2   = (const float*)d_in[14];
  const float* be2  = (const float*)d_in[15];
  float* out = (float*)d_out;

  // ---- workspace (~36.7 MB, layout unchanged) ----
  char* w = (char*)d_ws;
  float* cur  = (float*)w; w += (size_t)NTOT*DIM*4;
  float* tot  = (float*)w; w += (size_t)NTOT*DIM*4;
  float* tf   = (float*)w; w += (size_t)NTOT*DIM*4;
  float* pbuf = (float*)w; w += (size_t)NTOT*DIM*4;        // proj/ffn2 out; attn partials (2x bf16 = 4MB)
  float* x1   = (float*)w; w += (size_t)NTOT*DIM*4;
  u16* tbf    = (u16*)w;   w += (size_t)NTOT*DIM*2;        // spmm bf16; attn m/l
  u16* obf    = (u16*)w;   w += (size_t)NTOT*DIM*2;
  u16* x1b    = (u16*)w;   w += (size_t)NTOT*DIM*2;
  u16* hq     = (u16*)w;   w += (size_t)NTOT*FFD*2;        // qbf ∪ h
  u16* wqkvt  = (u16*)w;   w += (size_t)768*256*2;
  u16* wot    = (u16*)w;   w += (size_t)256*256*2;
  u16* w1t    = (u16*)w;   w += (size_t)1024*256*2;
  u16* w2t    = (u16*)w;   w += (size_t)256*1024*2;
  int* rowptr = (int*)w;   w += (size_t)(NTOT+1)*4;
  int* cnt    = (int*)w;   w += (size_t)NTOT*4;
  int* cursor = (int*)w;   w += (size_t)NTOT*4;
  int* ccol   = (int*)w;   w += (size_t)NEDGE*4;
  float* cval = (float*)w; w += (size_t)NEDGE*4;
  u16* qbf  = hq;
  u16* opbf = (u16*)pbuf;                      // 2 bf16 partials = 4 MB (pbuf region)
  float* mbuf = (float*)tbf;                   // [KSPLIT][NH][NTOT] f32 (256 KB)
  float* lbuf = mbuf + (size_t)KSPLIT*NH*NTOT; // 256 KB (inside dead tbf)

  k_zero<<<16, 256, 0, stream>>>(cnt, NTOT);
  k_embed<<<NTOT, 256, 0, stream>>>(pe, ae, qe, cur, tot);
  k_hist<<<NEDGE/256, 256, 0, stream>>>(adj_row, cnt);
  k_scan<<<1, 64, 0, stream>>>(cnt, rowptr, cursor);
  k_scatter<<<NEDGE/256, 256, 0, stream>>>(adj_row, adj_col, adj_val, cursor, ccol, cval);
  k_wconv_all<<<2304, 256, 0, stream>>>(Wqkv, Wo, W1, W2, wqkvt, wot, w1t, w2t);

  for (int blk = 0; blk < 3; ++blk){
    k_spmm<<<NTOT, 256, 0, stream>>>(rowptr, ccol, cval, cur, tf, tbf);
    k_gemm64<0,0,1><<<dim3(768/64, NTOT/64), 256, 0, stream>>>(tbf, wqkvt, nullptr, qbf, NTOT, 256, 768);
    k_attn_mfma<<<dim3(NTOT/64, NH, KSPLIT), 256, 0, stream>>>(qbf, opbf, mbuf, lbuf);
    k_attn_merge<<<NTOT*DIM/256, 256, 0, stream>>>(opbf, mbuf, lbuf, obf);
    k_gemm64<0,0,0><<<dim3(256/64, NTOT/64), 256, 0, stream>>>(obf, wot, nullptr, pbuf, NTOT, 256, 256);
    k_add_ln<1><<<NTOT, 256, 0, stream>>>(tf, pbuf, g1, be1, x1, x1b);
    k_gemm64<1,1,1><<<dim3(1024/64, NTOT/64), 256, 0, stream>>>(x1b, w1t, b1, hq, NTOT, 256, 1024);
    k_gemm64<0,1,0><<<dim3(256/64, NTOT/64), 256, 0, stream>>>(hq, w2t, b2, pbuf, NTOT, 1024, 256);
    if (blk < 2)
      k_add_ln_upd<0><<<NTOT, 256, 0, stream>>>(x1, pbuf, g2, be2, cur, tot, nullptr);
    else
      k_add_ln_upd<1><<<NTOT, 256, 0, stream>>>(x1, pbuf, g2, be2, cur, tot, out);
  }
}